// Round 6
// baseline (197.811 us; speedup 1.0000x reference)
//
#include <hip/hip_runtime.h>
#include <hip/hip_bf16.h>
#include <stdint.h>

// Problem constants
#define NTOT 8192   // B*(1+NPOS)
#define DD   128    // feature dim
#define BB   2048   // batch
#define NX   6144   // NPOS*B rows of x
// loss_neg subsample correction: log(4096/8191)
#define LOG_SUB_FRAC (-0.6930251f)
#define SQRT10 3.16227766017f
#define NBLK 2080   // 64*65/2 upper-tri tiles

typedef __attribute__((ext_vector_type(4))) float floatx4;  // MFMA C/D
typedef __attribute__((ext_vector_type(4))) int   intx4;
typedef __attribute__((ext_vector_type(8))) int   intx8;    // 32 B fp8 frag

#define GLOBAL_AS(p) ((const __attribute__((address_space(1))) void*)(p))
#define LDS_AS(p)    ((__attribute__((address_space(3))) void*)(p))

// DPP add: s + permuted(s). Row = 16 lanes on CDNA.
template <int CTRL>
__device__ __forceinline__ float dpp_add(float s) {
  return s + __int_as_float(
      __builtin_amdgcn_update_dpp(0, __float_as_int(s), CTRL, 0xF, 0xF, true));
}
// Sum across a 16-lane row (result in all 16 lanes): xor1, xor2, ror4, ror8.
__device__ __forceinline__ float row16_sum(float s) {
  s = dpp_add<0xB1>(s);   // quad_perm [1,0,3,2]
  s = dpp_add<0x4E>(s);   // quad_perm [2,3,0,1]
  s = dpp_add<0x124>(s);  // row_ror:4
  s = dpp_add<0x128>(s);  // row_ror:8
  return s;
}

// K1: L2-normalize rows of z = [x ; x_pair], scale by sqrt(10) (folds 1/TEMP
// into the MFMA so sim accumulates 10*cos directly) -> fp8 e4m3 (OCP).
// Fused positive dots (pure f32, unscaled). One wave per row.
// Zero-inits rowtotals[8192] + done-counter (stream-ordered before K2).
__global__ __launch_bounds__(256) void mp_norm(const float* __restrict__ x,
                                               const float* __restrict__ xp,
                                               uint8_t* __restrict__ znb8,
                                               float* __restrict__ pos,
                                               float* __restrict__ rowtotals,
                                               unsigned int* __restrict__ donecnt) {
  const int z = blockIdx.x * 256 + threadIdx.x;
  if (z < NTOT) rowtotals[z] = 0.f;
  if (z == 0) donecnt[0] = 0u;

  const int row  = blockIdx.x * 4 + (threadIdx.x >> 6);
  const int lane = threadIdx.x & 63;
  const bool isx = row < NX;
  const float* src = isx ? (x + (size_t)row * DD) : (xp + (size_t)(row - NX) * DD);
  float2 v = ((const float2*)src)[lane];
  float ss = v.x * v.x + v.y * v.y;

  float ssp = 0.f, d = 0.f;
  if (isx) {
    const int b = row & (BB - 1);
    float2 p = ((const float2*)(xp + (size_t)b * DD))[lane];
    ssp = p.x * p.x + p.y * p.y;
    d = v.x * p.x + v.y * p.y;
  }
  // wave-wide sums (all lanes get result)
  ss  = row16_sum(ss);  ss  += __shfl_xor(ss, 16, 64);  ss  += __shfl_xor(ss, 32, 64);
  if (isx) {
    ssp = row16_sum(ssp); ssp += __shfl_xor(ssp, 16, 64); ssp += __shfl_xor(ssp, 32, 64);
    d   = row16_sum(d);   d   += __shfl_xor(d, 16, 64);   d   += __shfl_xor(d, 32, 64);
  }
  const float rn = rsqrtf(ss);           // pure normalizer (for pos)
  const float rns = rn * SQRT10;         // scaled for znb8
  const int pk = __builtin_amdgcn_cvt_pk_fp8_f32(v.x * rns, v.y * rns, 0, false);
  *(uint16_t*)(znb8 + (size_t)row * DD + lane * 2) = (uint16_t)(pk & 0xffff);
  if (isx && lane == 0) pos[row] = d * rn * rsqrtf(ssp);
}

// K2: upper-triangle 128x128 tiles of 10*sim = Zs*Zs^T via MX-scaled fp8 MFMA
// (mfma_scale_f32_16x16x128_f8f6f4, fmt=e4m3, unit scales 0x7F -> x1.0):
// K=128 in ONE instruction at 2x non-scaled fp8 rate. K-permutation
// invariance: A/B frags use identical addressing from identically-laid-out
// tiles, so internal K ordering cancels in Z*Z^T — only row<->lane matters.
// LDS staging via global_load_lds (16 KB/tile), 16-B-pair XOR swizzle
// p^(row&7) -> uniform bank spread for ds_read_b128. 32 KB LDS, 4 blocks/CU.
// Epilogue: exp(acc) row+col sums -> atomicAdd rowtotals. Last block (device
// atomic counter) computes the final scalar — no separate tail kernel.
__global__ __launch_bounds__(256, 4) void mp_simexp(const uint8_t* __restrict__ znb8,
                                                    const float* __restrict__ pos,
                                                    float* __restrict__ rowtotals,
                                                    unsigned int* __restrict__ donecnt,
                                                    float* __restrict__ out) {
  __shared__ uint8_t Asmem[128 * 128];
  __shared__ uint8_t Bsmem[128 * 128];

  // Triangular decode: block t -> (bi, bj), bi <= bj.
  const int t = blockIdx.x;
  int bi = (int)((129.0f - sqrtf(16641.0f - 8.0f * (float)t)) * 0.5f);
  #define FCUM(r) ((r) * 64 - ((r) * ((r) - 1)) / 2)
  while (bi > 0 && FCUM(bi) > t) --bi;
  while (FCUM(bi + 1) <= t) ++bi;
  const int bj = bi + (t - FCUM(bi));
  const bool diag = (bi == bj);

  const int tid  = threadIdx.x;
  const int wave = tid >> 6, lane = tid & 63;
  const int lhi = lane >> 4, llo = lane & 15;

  const uint8_t* gA = znb8 + (size_t)bi * 128 * DD;
  const uint8_t* gB = znb8 + (size_t)bj * 128 * DD;

  // Stage tiles (16 KB each), 16 B/lane. Each wave-instr covers 8 rows
  // (128 B/row); lane l -> row c*8+(l>>3), 16-B pair p = (l&7)^(row&7)
  // (global source swizzled; LDS dest stays lane-contiguous). Diag: A only.
  #pragma unroll
  for (int tc = 0; tc < 4; ++tc) {
    const int c = wave * 4 + tc;
    const int row = c * 8 + (lane >> 3);
    const int p = (lane & 7) ^ (row & 7);
    const int roff = row * DD + p * 16;
    __builtin_amdgcn_global_load_lds(GLOBAL_AS(gA + roff), LDS_AS(&Asmem[c * 1024]), 16, 0, 0);
    if (!diag)
      __builtin_amdgcn_global_load_lds(GLOBAL_AS(gB + roff), LDS_AS(&Bsmem[c * 1024]), 16, 0, 0);
  }
  __syncthreads();
  const uint8_t* Bs = diag ? Asmem : Bsmem;

  // 2x2 wave grid; each wave computes a 64x64 subtile = 4x4 MFMA tiles,
  // one K=128 MFMA each. Frag: lane(llo=row, lhi): 32 contiguous K bytes at
  // lhi*32 = swizzled 16-B pairs (2*lhi)^(row&7), (2*lhi+1)^(row&7).
  // b[4] loaded up front (32 VGPRs); a streams per r (8) + acc 64 ≈ 110 live.
  const int wr = wave >> 1, wc = wave & 1;
  floatx4 acc[4][4] = {};
  intx8 bfrag[4];
  #pragma unroll
  for (int c = 0; c < 4; ++c) {
    const int row = wc * 64 + c * 16 + llo;
    const uint8_t* base = Bs + row * DD;
    intx4 lo = *(const intx4*)(base + (((2 * lhi)     ^ (row & 7)) << 4));
    intx4 hi = *(const intx4*)(base + (((2 * lhi + 1) ^ (row & 7)) << 4));
    bfrag[c] = intx8{lo.x, lo.y, lo.z, lo.w, hi.x, hi.y, hi.z, hi.w};
  }
  #pragma unroll
  for (int r = 0; r < 4; ++r) {
    const int row = wr * 64 + r * 16 + llo;
    const uint8_t* base = Asmem + row * DD;
    intx4 lo = *(const intx4*)(base + (((2 * lhi)     ^ (row & 7)) << 4));
    intx4 hi = *(const intx4*)(base + (((2 * lhi + 1) ^ (row & 7)) << 4));
    intx8 afrag = intx8{lo.x, lo.y, lo.z, lo.w, hi.x, hi.y, hi.z, hi.w};
    #pragma unroll
    for (int c = 0; c < 4; ++c)
      acc[r][c] = __builtin_amdgcn_mfma_scale_f32_16x16x128_f8f6f4(
          afrag, bfrag[c], acc[r][c], 0, 0, 0, 0x7F7F7F7F, 0, 0x7F7F7F7F);
  }

  // Epilogue: e = exp(acc) (acc is already 10*cos); diag masked on the 64
  // diagonal blocks only (uniform branch). Row sums + col sums.
  // C/D layout: col = lane&15, row = (lane>>4)*4 + reg.
  float rowacc[4][4];
  #pragma unroll
  for (int r = 0; r < 4; ++r)
    #pragma unroll
    for (int j = 0; j < 4; ++j) rowacc[r][j] = 0.f;
  float colacc[4] = {0.f, 0.f, 0.f, 0.f};

  if (diag) {
    #pragma unroll
    for (int r = 0; r < 4; ++r) {
      #pragma unroll
      for (int c = 0; c < 4; ++c) {
        const int col = wc * 64 + c * 16 + llo;
        #pragma unroll
        for (int j = 0; j < 4; ++j) {
          const int row = wr * 64 + r * 16 + lhi * 4 + j;
          float e = __expf(acc[r][c][j]);
          if (row == col) e = 0.f;
          rowacc[r][j] += e;
          colacc[c] += e;
        }
      }
    }
  } else {
    #pragma unroll
    for (int r = 0; r < 4; ++r) {
      #pragma unroll
      for (int c = 0; c < 4; ++c) {
        #pragma unroll
        for (int j = 0; j < 4; ++j) {
          float e = __expf(acc[r][c][j]);
          rowacc[r][j] += e;
          colacc[c] += e;
        }
      }
    }
  }

  // Row sums: DPP-reduce across llo; lane llo==j issues the atomic for reg j.
  float* rowdst = rowtotals + bi * 128 + wr * 64;
  #pragma unroll
  for (int r = 0; r < 4; ++r) {
    #pragma unroll
    for (int j = 0; j < 4; ++j) {
      float s = row16_sum(rowacc[r][j]);
      if (llo == j) atomicAdd(&rowdst[r * 16 + lhi * 4 + j], s);
    }
  }
  // Col sums (skip on diag: rows already fully counted by rowsums there).
  if (!diag) {
    float* coldst = rowtotals + bj * 128 + wc * 64;
    #pragma unroll
    for (int c = 0; c < 4; ++c) {
      float s = colacc[c];
      s += __shfl_xor(s, 16, 64);
      s += __shfl_xor(s, 32, 64);
      if (lhi == 0) atomicAdd(&coldst[c * 16 + llo], s);  // 16 lanes, coalesced
    }
  }

  // Last-block-done tail: final scalar in this kernel (no tail launch).
  __threadfence();
  __shared__ unsigned int lastFlag;
  if (tid == 0) lastFlag = (atomicAdd(donecnt, 1u) == NBLK - 1) ? 1u : 0u;
  __syncthreads();
  if (lastFlag) {
    __threadfence();
    // rowtotals read through atomics (same coherence point as the writes).
    float l = 0.f;
    #pragma unroll
    for (int k = 0; k < 32; ++k)
      l += logf(atomicAdd(&rowtotals[k * 256 + tid], 0.f));
    float p = 0.f;
    #pragma unroll
    for (int k = 0; k < 24; ++k) p += pos[k * 256 + tid];  // prior-kernel data
    #pragma unroll
    for (int m = 1; m < 64; m <<= 1) {
      l += __shfl_xor(l, m, 64);
      p += __shfl_xor(p, m, 64);
    }
    __shared__ float rl[4], rp[4];
    if ((tid & 63) == 0) { rl[tid >> 6] = l; rp[tid >> 6] = p; }
    __syncthreads();
    if (tid == 0) {
      const float S = rl[0] + rl[1] + rl[2] + rl[3];
      const float P = rp[0] + rp[1] + rp[2] + rp[3];
      const float loss_neg = S / (float)NTOT + LOG_SUB_FRAC;
      const float loss_pos = P * (10.0f / (float)NX);  // WEIGHT/TEMP/(B*NPOS)
      out[0] = loss_neg - loss_pos;
    }
  }
}

extern "C" void kernel_launch(void* const* d_in, const int* in_sizes, int n_in,
                              void* d_out, int out_size, void* d_ws, size_t ws_size,
                              hipStream_t stream) {
  const float* x  = (const float*)d_in[0];   // [6144, 128] f32
  const float* xp = (const float*)d_in[1];   // [2048, 128] f32
  float* out = (float*)d_out;                // scalar f32

  char* ws = (char*)d_ws;
  uint8_t* znb8          = (uint8_t*)ws;                             // 1 MB
  float* pos             = (float*)(ws + (1u << 20));                // 24 KB
  float* rowtotals       = (float*)(ws + (1u << 20) + (32u << 10));  // 32 KB
  unsigned int* donecnt  = (unsigned int*)(ws + (1u << 20) + (64u << 10));

  mp_norm<<<NTOT / 4, 256, 0, stream>>>(x, xp, znb8, pos, rowtotals, donecnt);
  mp_simexp<<<NBLK, 256, 0, stream>>>(znb8, pos, rowtotals, donecnt, out);
}

// Round 7
// 91.820 us; speedup vs baseline: 2.1543x; 2.1543x over previous
//
#include <hip/hip_runtime.h>
#include <hip/hip_bf16.h>
#include <stdint.h>

// Problem constants
#define NTOT 8192   // B*(1+NPOS)
#define DD   128    // feature dim
#define BB   2048   // batch
#define NX   6144   // NPOS*B rows of x
// loss_neg subsample correction: log(4096/8191)
#define LOG_SUB_FRAC (-0.6930251f)
#define SQRT10 3.16227766017f
#define NBLK 2080   // 64*65/2 upper-tri tiles

typedef __attribute__((ext_vector_type(4))) float floatx4;  // MFMA C/D
typedef __attribute__((ext_vector_type(4))) int   intx4;
typedef __attribute__((ext_vector_type(8))) int   intx8;    // 32 B fp8 frag

#define GLOBAL_AS(p) ((const __attribute__((address_space(1))) void*)(p))
#define LDS_AS(p)    ((__attribute__((address_space(3))) void*)(p))

// DPP add: s + permuted(s). Row = 16 lanes on CDNA.
template <int CTRL>
__device__ __forceinline__ float dpp_add(float s) {
  return s + __int_as_float(
      __builtin_amdgcn_update_dpp(0, __float_as_int(s), CTRL, 0xF, 0xF, true));
}
// Sum across a 16-lane row (result in all 16 lanes): xor1, xor2, ror4, ror8.
__device__ __forceinline__ float row16_sum(float s) {
  s = dpp_add<0xB1>(s);   // quad_perm [1,0,3,2]
  s = dpp_add<0x4E>(s);   // quad_perm [2,3,0,1]
  s = dpp_add<0x124>(s);  // row_ror:4
  s = dpp_add<0x128>(s);  // row_ror:8
  return s;
}

// K1: L2-normalize rows of z = [x ; x_pair], scale by sqrt(10) (folds 1/TEMP
// into the MFMA so sim accumulates 10*cos directly) -> fp8 e4m3 (OCP).
// Fused positive dots (pure f32, unscaled). One wave per row.
// Zero-inits rowtotals[8192] (atomic target for K2) — stream-ordered.
__global__ __launch_bounds__(256) void mp_norm(const float* __restrict__ x,
                                               const float* __restrict__ xp,
                                               uint8_t* __restrict__ znb8,
                                               float* __restrict__ pos,
                                               float* __restrict__ rowtotals) {
  const int z = blockIdx.x * 256 + threadIdx.x;
  if (z < NTOT) rowtotals[z] = 0.f;

  const int row  = blockIdx.x * 4 + (threadIdx.x >> 6);
  const int lane = threadIdx.x & 63;
  const bool isx = row < NX;
  const float* src = isx ? (x + (size_t)row * DD) : (xp + (size_t)(row - NX) * DD);
  float2 v = ((const float2*)src)[lane];
  float ss = v.x * v.x + v.y * v.y;

  float ssp = 0.f, d = 0.f;
  if (isx) {
    const int b = row & (BB - 1);
    float2 p = ((const float2*)(xp + (size_t)b * DD))[lane];
    ssp = p.x * p.x + p.y * p.y;
    d = v.x * p.x + v.y * p.y;
  }
  // wave-wide sums (all lanes get result)
  ss  = row16_sum(ss);  ss  += __shfl_xor(ss, 16, 64);  ss  += __shfl_xor(ss, 32, 64);
  if (isx) {
    ssp = row16_sum(ssp); ssp += __shfl_xor(ssp, 16, 64); ssp += __shfl_xor(ssp, 32, 64);
    d   = row16_sum(d);   d   += __shfl_xor(d, 16, 64);   d   += __shfl_xor(d, 32, 64);
  }
  const float rn = rsqrtf(ss);           // pure normalizer (for pos)
  const float rns = rn * SQRT10;         // scaled for znb8
  const int pk = __builtin_amdgcn_cvt_pk_fp8_f32(v.x * rns, v.y * rns, 0, false);
  *(uint16_t*)(znb8 + (size_t)row * DD + lane * 2) = (uint16_t)(pk & 0xffff);
  if (isx && lane == 0) pos[row] = d * rn * rsqrtf(ssp);
}

// K2: upper-triangle 128x128 tiles of 10*sim = Zs*Zs^T via MX-scaled fp8 MFMA
// (mfma_scale_f32_16x16x128_f8f6f4, fmt=e4m3, unit scales 0x7F -> x1.0):
// K=128 in ONE instruction at 2x non-scaled fp8 rate (validated R6: MfmaUtil
// showed the MFMA ran at full rate; the R6 regression was the per-block
// __threadfence L2-writeback, now removed — coherence via kernel boundary).
// LDS staging via global_load_lds (16 KB/tile), 16-B-pair XOR swizzle
// p^(row&7). 32 KB LDS, 4 blocks/CU. Epilogue: exp(acc) row+col sums ->
// atomicAdd rowtotals. NO device fences on the hot path (R6 lesson).
__global__ __launch_bounds__(256, 4) void mp_simexp(const uint8_t* __restrict__ znb8,
                                                    float* __restrict__ rowtotals) {
  __shared__ uint8_t Asmem[128 * 128];
  __shared__ uint8_t Bsmem[128 * 128];

  // Triangular decode: block t -> (bi, bj), bi <= bj.
  const int t = blockIdx.x;
  int bi = (int)((129.0f - sqrtf(16641.0f - 8.0f * (float)t)) * 0.5f);
  #define FCUM(r) ((r) * 64 - ((r) * ((r) - 1)) / 2)
  while (bi > 0 && FCUM(bi) > t) --bi;
  while (FCUM(bi + 1) <= t) ++bi;
  const int bj = bi + (t - FCUM(bi));
  const bool diag = (bi == bj);

  const int tid  = threadIdx.x;
  const int wave = tid >> 6, lane = tid & 63;
  const int lhi = lane >> 4, llo = lane & 15;

  const uint8_t* gA = znb8 + (size_t)bi * 128 * DD;
  const uint8_t* gB = znb8 + (size_t)bj * 128 * DD;

  // Stage tiles (16 KB each), 16 B/lane. Each wave-instr covers 8 rows
  // (128 B/row); lane l -> row c*8+(l>>3), 16-B pair p = (l&7)^(row&7)
  // (global source swizzled; LDS dest stays lane-contiguous). Diag: A only.
  #pragma unroll
  for (int tc = 0; tc < 4; ++tc) {
    const int c = wave * 4 + tc;
    const int row = c * 8 + (lane >> 3);
    const int p = (lane & 7) ^ (row & 7);
    const int roff = row * DD + p * 16;
    __builtin_amdgcn_global_load_lds(GLOBAL_AS(gA + roff), LDS_AS(&Asmem[c * 1024]), 16, 0, 0);
    if (!diag)
      __builtin_amdgcn_global_load_lds(GLOBAL_AS(gB + roff), LDS_AS(&Bsmem[c * 1024]), 16, 0, 0);
  }
  __syncthreads();
  const uint8_t* Bs = diag ? Asmem : Bsmem;

  // 2x2 wave grid; each wave computes a 64x64 subtile = 4x4 MFMA tiles,
  // one K=128 MFMA each. Frag: lane(llo=row, lhi): 32 contiguous K bytes at
  // lhi*32 = swizzled 16-B pairs (2*lhi)^(row&7), (2*lhi+1)^(row&7).
  // K-permutation invariance: A/B frags use identical addressing from
  // identically-laid-out tiles, so internal K ordering cancels in Z*Z^T.
  const int wr = wave >> 1, wc = wave & 1;
  floatx4 acc[4][4] = {};
  intx8 bfrag[4];
  #pragma unroll
  for (int c = 0; c < 4; ++c) {
    const int row = wc * 64 + c * 16 + llo;
    const uint8_t* base = Bs + row * DD;
    intx4 lo = *(const intx4*)(base + (((2 * lhi)     ^ (row & 7)) << 4));
    intx4 hi = *(const intx4*)(base + (((2 * lhi + 1) ^ (row & 7)) << 4));
    bfrag[c] = intx8{lo.x, lo.y, lo.z, lo.w, hi.x, hi.y, hi.z, hi.w};
  }
  #pragma unroll
  for (int r = 0; r < 4; ++r) {
    const int row = wr * 64 + r * 16 + llo;
    const uint8_t* base = Asmem + row * DD;
    intx4 lo = *(const intx4*)(base + (((2 * lhi)     ^ (row & 7)) << 4));
    intx4 hi = *(const intx4*)(base + (((2 * lhi + 1) ^ (row & 7)) << 4));
    intx8 afrag = intx8{lo.x, lo.y, lo.z, lo.w, hi.x, hi.y, hi.z, hi.w};
    #pragma unroll
    for (int c = 0; c < 4; ++c)
      acc[r][c] = __builtin_amdgcn_mfma_scale_f32_16x16x128_f8f6f4(
          afrag, bfrag[c], acc[r][c], 0, 0, 0, 0x7F7F7F7F, 0, 0x7F7F7F7F);
  }

  // Epilogue: e = exp(acc) (acc is already 10*cos); diag masked on the 64
  // diagonal blocks only (uniform branch). Row sums + col sums.
  // C/D layout: col = lane&15, row = (lane>>4)*4 + reg.
  float rowacc[4][4];
  #pragma unroll
  for (int r = 0; r < 4; ++r)
    #pragma unroll
    for (int j = 0; j < 4; ++j) rowacc[r][j] = 0.f;
  float colacc[4] = {0.f, 0.f, 0.f, 0.f};

  if (diag) {
    #pragma unroll
    for (int r = 0; r < 4; ++r) {
      #pragma unroll
      for (int c = 0; c < 4; ++c) {
        const int col = wc * 64 + c * 16 + llo;
        #pragma unroll
        for (int j = 0; j < 4; ++j) {
          const int row = wr * 64 + r * 16 + lhi * 4 + j;
          float e = __expf(acc[r][c][j]);
          if (row == col) e = 0.f;
          rowacc[r][j] += e;
          colacc[c] += e;
        }
      }
    }
  } else {
    #pragma unroll
    for (int r = 0; r < 4; ++r) {
      #pragma unroll
      for (int c = 0; c < 4; ++c) {
        #pragma unroll
        for (int j = 0; j < 4; ++j) {
          float e = __expf(acc[r][c][j]);
          rowacc[r][j] += e;
          colacc[c] += e;
        }
      }
    }
  }

  // Row sums: DPP-reduce across llo; lane llo==j issues the atomic for reg j.
  float* rowdst = rowtotals + bi * 128 + wr * 64;
  #pragma unroll
  for (int r = 0; r < 4; ++r) {
    #pragma unroll
    for (int j = 0; j < 4; ++j) {
      float s = row16_sum(rowacc[r][j]);
      if (llo == j) atomicAdd(&rowdst[r * 16 + lhi * 4 + j], s);
    }
  }
  // Col sums (skip on diag: rows already fully counted by rowsums there).
  if (!diag) {
    float* coldst = rowtotals + bj * 128 + wc * 64;
    #pragma unroll
    for (int c = 0; c < 4; ++c) {
      float s = colacc[c];
      s += __shfl_xor(s, 16, 64);
      s += __shfl_xor(s, 32, 64);
      if (lhi == 0) atomicAdd(&coldst[c * 16 + llo], s);  // 16 lanes, coalesced
    }
  }
}

// K3: fused tail — per-row log + mean, pos-sum, final scalar. One block.
__global__ __launch_bounds__(1024) void mp_tail(const float* __restrict__ rowtotals,
                                                const float* __restrict__ pos,
                                                float* __restrict__ out) {
  const int tid = threadIdx.x;
  float l = 0.f;
  #pragma unroll
  for (int k = 0; k < 8; ++k) l += logf(rowtotals[k * 1024 + tid]);
  float p = 0.f;
  for (int t = tid; t < NX; t += 1024) p += pos[t];
  #pragma unroll
  for (int m = 1; m < 64; m <<= 1) {
    l += __shfl_xor(l, m, 64);
    p += __shfl_xor(p, m, 64);
  }
  __shared__ float rl[16], rp[16];
  if ((tid & 63) == 0) { rl[tid >> 6] = l; rp[tid >> 6] = p; }
  __syncthreads();
  if (tid == 0) {
    float S = 0.f, P = 0.f;
    #pragma unroll
    for (int w = 0; w < 16; ++w) { S += rl[w]; P += rp[w]; }
    const float loss_neg = S / (float)NTOT + LOG_SUB_FRAC;
    const float loss_pos = P * (10.0f / (float)NX);  // WEIGHT * (1/TEMP) / (B*NPOS)
    out[0] = loss_neg - loss_pos;
  }
}

extern "C" void kernel_launch(void* const* d_in, const int* in_sizes, int n_in,
                              void* d_out, int out_size, void* d_ws, size_t ws_size,
                              hipStream_t stream) {
  const float* x  = (const float*)d_in[0];   // [6144, 128] f32
  const float* xp = (const float*)d_in[1];   // [2048, 128] f32
  float* out = (float*)d_out;                // scalar f32

  char* ws = (char*)d_ws;
  uint8_t* znb8    = (uint8_t*)ws;                              // 1 MB
  float* pos       = (float*)(ws + (1u << 20));                 // 24 KB
  float* rowtotals = (float*)(ws + (1u << 20) + (32u << 10));   // 32 KB

  mp_norm<<<NTOT / 4, 256, 0, stream>>>(x, xp, znb8, pos, rowtotals);
  mp_simexp<<<NBLK, 256, 0, stream>>>(znb8, rowtotals);
  mp_tail<<<1, 1024, 0, stream>>>(rowtotals, pos, out);
}